// Round 1
// baseline (1122.477 us; speedup 1.0000x reference)
//
#include <hip/hip_runtime.h>

// Problem constants (reference hardcodes B=16, S=64)
#define BATCH 16
#define HW    64
#define PPB   (HW * HW)          // 4096 pixels per batch image
#define NPIX  (BATCH * PPB)      // 65536 total pixels
#define NELEM (NPIX * 4)         // 262144 loss terms

__global__ void zero_out_kernel(float* out) {
    out[0] = 0.0f;
}

__global__ __launch_bounds__(256) void smpl_loss_kernel(
        const float* __restrict__ corr,   // [B, 4096, 4096]
        const float* __restrict__ flow,   // [B, 2, 64, 64]
        const float* __restrict__ vis,    // [B, 1, 64, 64]
        float* __restrict__ out) {
    const int pix = blockIdx.x * blockDim.x + threadIdx.x;  // 0..65535
    const int b = pix >> 12;          // / 4096
    const int p = pix & 4095;         // y*64 + x

    // gt grid coords: channel 0 -> x (scaled by w-1), channel 1 -> y (scaled by h-1)
    const float gxv = flow[(size_t)(b * 2 + 0) * PPB + p];
    const float gyv = flow[(size_t)(b * 2 + 1) * PPB + p];
    const float gx = (gxv + 1.0f) * 31.5f;   // (w-1)/2 = 31.5
    const float gy = (gyv + 1.0f) * 31.5f;
    const float fx = floorf(gx);
    const float fy = floorf(gy);

    const float ax = fx + 1.0f - gx;   // x residual (low side)
    const float bx = gx - fx;
    const float ay = fy + 1.0f - gy;   // y residual (low side)
    const float by = gy - fy;

    // weights ordered per offsets (0,0),(0,1),(1,0),(1,1)
    float wt[4];
    wt[0] = ay * ax;
    wt[1] = ay * bx;
    wt[2] = by * ax;
    wt[3] = by * bx;

    const float v = vis[(size_t)b * PPB + p];
    const float* row = corr + ((size_t)b * PPB + p) * (size_t)PPB;

    const int ox[4] = {0, 0, 1, 1};  // applied to fy
    const int oy[4] = {0, 1, 0, 1};  // applied to fx

    float s = 0.0f;
#pragma unroll
    for (int i = 0; i < 4; ++i) {
        float xi = fminf(fmaxf(fy + (float)ox[i], 0.0f), 63.0f);
        float yi = fminf(fmaxf(fx + (float)oy[i], 0.0f), 63.0f);
        int idx = (int)(xi * 64.0f + yi);
        float g = row[idx];
        s += fabsf(g * v - wt[i] * v);
    }

    // wave-64 reduction
#pragma unroll
    for (int o = 32; o > 0; o >>= 1) s += __shfl_down(s, o, 64);

    __shared__ float lds[4];  // 256 threads / 64 = 4 waves
    const int lane = threadIdx.x & 63;
    const int wave = threadIdx.x >> 6;
    if (lane == 0) lds[wave] = s;
    __syncthreads();
    if (threadIdx.x == 0) {
        float t = (lds[0] + lds[1]) + (lds[2] + lds[3]);
        atomicAdd(out, t * (1.0f / (float)NELEM));
    }
}

extern "C" void kernel_launch(void* const* d_in, const int* in_sizes, int n_in,
                              void* d_out, int out_size, void* d_ws, size_t ws_size,
                              hipStream_t stream) {
    const float* corr = (const float*)d_in[0];  // [16, 4096, 4096]
    const float* flow = (const float*)d_in[1];  // [16, 2, 64, 64]
    const float* vis  = (const float*)d_in[2];  // [16, 1, 64, 64]
    float* out = (float*)d_out;                 // scalar

    zero_out_kernel<<<1, 1, 0, stream>>>(out);
    smpl_loss_kernel<<<NPIX / 256, 256, 0, stream>>>(corr, flow, vis, out);
}